// Round 1
// baseline (575.228 us; speedup 1.0000x reference)
//
#include <hip/hip_runtime.h>

typedef _Float16 f16;
typedef _Float16 f16x4_t __attribute__((ext_vector_type(4)));
typedef _Float16 f16x8_t __attribute__((ext_vector_type(8)));
typedef float    f32x4_t __attribute__((ext_vector_type(4)));

#define HD 512          // h
#define CD 256          // c
#define ND 512          // N (codebook)
#define MROWS (4*24*2048)
#define BM 128
#define NTHR 512
#define TINV 10.0f      // 1/TEMP

// ---------------- prep: M = Wp(512x256) @ Wq(256x512) -> fp16 [512][512]; sb[n] = sum_c b[c]*Wp[n][c]
__global__ void prep_M(const float* __restrict__ Wp, const float* __restrict__ Wq,
                       const float* __restrict__ bq, f16* __restrict__ Mt,
                       float* __restrict__ sb) {
  const int n = blockIdx.x;   // 0..511
  const int t = threadIdx.x;  // 0..255
  __shared__ float wpr[CD];
  __shared__ float sred[CD];
  wpr[t] = Wp[n * CD + t];
  __syncthreads();
  float a0 = 0.f, a1 = 0.f;
  #pragma unroll 8
  for (int c = 0; c < CD; ++c) {
    const float w = wpr[c];
    a0 = fmaf(w, Wq[c * HD + t], a0);
    a1 = fmaf(w, Wq[c * HD + t + 256], a1);
  }
  Mt[n * HD + t] = (f16)a0;
  Mt[n * HD + t + 256] = (f16)a1;
  sred[t] = wpr[t] * bq[t];
  __syncthreads();
  for (int s = 128; s > 0; s >>= 1) {
    if (t < s) sred[t] += sred[t + s];
    __syncthreads();
  }
  if (t == 0) sb[n] = sred[0];
}

// ---------------- prep: WpT fp16 [256][512], WpT[c][n] = Wp[n][c]
__global__ void prep_WpT(const float* __restrict__ Wp, f16* __restrict__ WpT) {
  const int c = blockIdx.x;   // 0..255
  const int n = threadIdx.x;  // 0..511
  WpT[c * ND + n] = (f16)Wp[n * CD + c];
}

// ---------------- fused main: scores = H@Mt^T (+sb), softmax, Q out, P = Q@Wp
__global__ __launch_bounds__(NTHR, 2)
void fused_main(const float* __restrict__ Hl, const f16* __restrict__ Mt,
                const f16* __restrict__ WpT, const float* __restrict__ sb,
                float* __restrict__ outP, float* __restrict__ outQ) {
  __shared__ f16 AQ[BM * HD];        // 128 KiB: holds H fp16, then Q fp16 (XOR-swizzled rows)
  __shared__ float red[BM][4];
  __shared__ float rstat[BM];

  const int tid  = threadIdx.x;
  const int lane = tid & 63;
  const int wid  = tid >> 6;         // 0..7
  const int wr   = wid >> 2;         // 0..1 (row half)
  const int wc   = wid & 3;          // 0..3 (col quarter)
  const int q4   = lane >> 4;        // 0..3
  const int l16  = lane & 15;
  const long rowbase = (long)blockIdx.x * BM;

  // ---- stage H: 128 rows x 512 fp32 -> fp16 LDS (swizzled) ----
  {
    const float4* __restrict__ src = (const float4*)(Hl + rowbase * HD);
    #pragma unroll
    for (int it = 0; it < (BM * HD / 4) / NTHR; ++it) {   // 32 iters
      const int f = it * NTHR + tid;                      // float4 index
      const float4 v = src[f];
      const int row = f >> 7;                             // f / 128
      int byteoff = row * (HD * 2) + ((f & 127) << 3);    // (f%128)*4 cols * 2B
      byteoff ^= (row & 7) << 4;
      f16x4_t h;
      h[0] = (f16)v.x; h[1] = (f16)v.y; h[2] = (f16)v.z; h[3] = (f16)v.w;
      *(f16x4_t*)((char*)AQ + byteoff) = h;
    }
  }
  __syncthreads();

  // ---- GEMM1: scores[128][512] = H_f16 @ Mt^T, fp32 acc ----
  f32x4_t acc[4][8];
  #pragma unroll
  for (int i = 0; i < 4; ++i)
    #pragma unroll
    for (int j = 0; j < 8; ++j)
      #pragma unroll
      for (int k = 0; k < 4; ++k) acc[i][j][k] = 0.f;

  {
    const f16* __restrict__ mb = Mt + (long)(wc * 128 + l16) * HD + q4 * 8;
    const int arow0 = wr * 64 + l16;
    for (int ks = 0; ks < 16; ++ks) {
      f16x8_t a[4];
      #pragma unroll
      for (int mf = 0; mf < 4; ++mf) {
        const int arow = arow0 + mf * 16;
        int byteoff = arow * (HD * 2) + ks * 64 + q4 * 16;
        byteoff ^= (arow & 7) << 4;
        a[mf] = *(const f16x8_t*)((const char*)AQ + byteoff);
      }
      #pragma unroll
      for (int nf = 0; nf < 8; ++nf) {
        const f16x8_t b = *(const f16x8_t*)(mb + nf * 16 * HD + ks * 32);
        #pragma unroll
        for (int mf = 0; mf < 4; ++mf)
          acc[mf][nf] = __builtin_amdgcn_mfma_f32_16x16x32_f16(a[mf], b, acc[mf][nf], 0, 0, 0);
      }
    }
  }

  // ---- softmax over N=512 (rows span all 4 wc waves) ----
  // thread holds rows rloc = wr*64 + mf*16 + q4*4 + r, cols wc*128 + nf*16 + l16
  float sb10[8];
  #pragma unroll
  for (int nf = 0; nf < 8; ++nf) sb10[nf] = sb[wc * 128 + nf * 16 + l16] * TINV;

  #pragma unroll
  for (int mf = 0; mf < 4; ++mf)
    #pragma unroll
    for (int nf = 0; nf < 8; ++nf)
      #pragma unroll
      for (int r = 0; r < 4; ++r)
        acc[mf][nf][r] = fmaf(acc[mf][nf][r], TINV, sb10[nf]);   // logits

  // per-(mf,r) max over nf, then over 16 lanes
  float pm[4][4];
  #pragma unroll
  for (int mf = 0; mf < 4; ++mf)
    #pragma unroll
    for (int r = 0; r < 4; ++r) {
      float m = -3.0e38f;
      #pragma unroll
      for (int nf = 0; nf < 8; ++nf) m = fmaxf(m, acc[mf][nf][r]);
      pm[mf][r] = m;
    }
  #pragma unroll
  for (int st = 8; st >= 1; st >>= 1)
    #pragma unroll
    for (int mf = 0; mf < 4; ++mf)
      #pragma unroll
      for (int r = 0; r < 4; ++r)
        pm[mf][r] = fmaxf(pm[mf][r], __shfl_xor(pm[mf][r], st, 64));

  if (l16 == 0) {
    #pragma unroll
    for (int mf = 0; mf < 4; ++mf)
      #pragma unroll
      for (int r = 0; r < 4; ++r)
        red[wr * 64 + mf * 16 + q4 * 4 + r][wc] = pm[mf][r];
  }
  __syncthreads();
  if (tid < BM)
    rstat[tid] = fmaxf(fmaxf(red[tid][0], red[tid][1]), fmaxf(red[tid][2], red[tid][3]));
  __syncthreads();

  float rm[4][4];
  #pragma unroll
  for (int mf = 0; mf < 4; ++mf)
    #pragma unroll
    for (int r = 0; r < 4; ++r)
      rm[mf][r] = rstat[wr * 64 + mf * 16 + q4 * 4 + r];

  float ps[4][4];
  #pragma unroll
  for (int mf = 0; mf < 4; ++mf)
    #pragma unroll
    for (int r = 0; r < 4; ++r) ps[mf][r] = 0.f;
  #pragma unroll
  for (int mf = 0; mf < 4; ++mf)
    #pragma unroll
    for (int nf = 0; nf < 8; ++nf)
      #pragma unroll
      for (int r = 0; r < 4; ++r) {
        const float e = __expf(acc[mf][nf][r] - rm[mf][r]);
        acc[mf][nf][r] = e;
        ps[mf][r] += e;
      }
  #pragma unroll
  for (int st = 8; st >= 1; st >>= 1)
    #pragma unroll
    for (int mf = 0; mf < 4; ++mf)
      #pragma unroll
      for (int r = 0; r < 4; ++r)
        ps[mf][r] += __shfl_xor(ps[mf][r], st, 64);

  if (l16 == 0) {
    #pragma unroll
    for (int mf = 0; mf < 4; ++mf)
      #pragma unroll
      for (int r = 0; r < 4; ++r)
        red[wr * 64 + mf * 16 + q4 * 4 + r][wc] = ps[mf][r];
  }
  __syncthreads();
  if (tid < BM)
    rstat[tid] = 1.0f / (red[tid][0] + red[tid][1] + red[tid][2] + red[tid][3]);
  __syncthreads();

  float rinv[4][4];
  #pragma unroll
  for (int mf = 0; mf < 4; ++mf)
    #pragma unroll
    for (int r = 0; r < 4; ++r)
      rinv[mf][r] = rstat[wr * 64 + mf * 16 + q4 * 4 + r];

  // ---- Q out (fp32) + Q fp16 back into AQ (H fully consumed) ----
  #pragma unroll
  for (int mf = 0; mf < 4; ++mf)
    #pragma unroll
    for (int nf = 0; nf < 8; ++nf)
      #pragma unroll
      for (int r = 0; r < 4; ++r) {
        const int rloc = wr * 64 + mf * 16 + q4 * 4 + r;
        const int col  = wc * 128 + nf * 16 + l16;
        const float q = acc[mf][nf][r] * rinv[mf][r];
        outQ[(rowbase + rloc) * ND + col] = q;
        int byteoff = rloc * (ND * 2) + col * 2;
        byteoff ^= (rloc & 7) << 4;
        *(f16*)((char*)AQ + byteoff) = (f16)q;
      }
  __syncthreads();

  // ---- GEMM3: P[128][256] = Q_f16 @ Wp  (B = WpT[c][n], B^T layout) ----
  f32x4_t acc2[4][4];
  #pragma unroll
  for (int i = 0; i < 4; ++i)
    #pragma unroll
    for (int j = 0; j < 4; ++j)
      #pragma unroll
      for (int k = 0; k < 4; ++k) acc2[i][j][k] = 0.f;

  {
    const f16* __restrict__ wb = WpT + (long)(wc * 64 + l16) * ND + q4 * 8;
    const int arow0 = wr * 64 + l16;
    for (int ks = 0; ks < 16; ++ks) {
      f16x8_t a[4];
      #pragma unroll
      for (int mf = 0; mf < 4; ++mf) {
        const int arow = arow0 + mf * 16;
        int byteoff = arow * (ND * 2) + ks * 64 + q4 * 16;
        byteoff ^= (arow & 7) << 4;
        a[mf] = *(const f16x8_t*)((const char*)AQ + byteoff);
      }
      #pragma unroll
      for (int nf = 0; nf < 4; ++nf) {
        const f16x8_t b = *(const f16x8_t*)(wb + nf * 16 * ND + ks * 32);
        #pragma unroll
        for (int mf = 0; mf < 4; ++mf)
          acc2[mf][nf] = __builtin_amdgcn_mfma_f32_16x16x32_f16(a[mf], b, acc2[mf][nf], 0, 0, 0);
      }
    }
  }

  #pragma unroll
  for (int mf = 0; mf < 4; ++mf)
    #pragma unroll
    for (int nf = 0; nf < 4; ++nf)
      #pragma unroll
      for (int r = 0; r < 4; ++r) {
        const int rloc = wr * 64 + mf * 16 + q4 * 4 + r;
        const int col  = wc * 64 + nf * 16 + l16;
        outP[(rowbase + rloc) * CD + col] = acc2[mf][nf][r];
      }
}

extern "C" void kernel_launch(void* const* d_in, const int* in_sizes, int n_in,
                              void* d_out, int out_size, void* d_ws, size_t ws_size,
                              hipStream_t stream) {
  const float* Hl = (const float*)d_in[0];   // (B,T,V,H)
  const float* Wp = (const float*)d_in[1];   // (N,C)
  const float* Wq = (const float*)d_in[2];   // (C,H)
  const float* bq = (const float*)d_in[3];   // (C,)

  float* outP = (float*)d_out;                         // (M, C)
  float* outQ = (float*)d_out + (long)MROWS * CD;      // (M, N)

  f16*   Mt  = (f16*)d_ws;                                        // 512*512*2 = 512 KiB
  f16*   WpT = (f16*)((char*)d_ws + ND * HD * 2);                 // 256*512*2 = 256 KiB
  float* sb  = (float*)((char*)d_ws + ND * HD * 2 + CD * ND * 2); // 2 KiB

  prep_M  <<<ND, CD, 0, stream>>>(Wp, Wq, bq, Mt, sb);
  prep_WpT<<<CD, ND, 0, stream>>>(Wp, WpT);
  fused_main<<<MROWS / BM, NTHR, 0, stream>>>(Hl, Mt, WpT, sb, outP, outQ);
}